// Round 8
// baseline (164.783 us; speedup 1.0000x reference)
//
#include <hip/hip_runtime.h>
#include <hip/hip_bf16.h>

#define HW_ 36864
#define W_ 192
#define H_ 192
#define NPIX_ 73728
#define TWO_PI_F 6.283185307179586f

typedef __attribute__((ext_vector_type(8))) short bfrag;
typedef __attribute__((ext_vector_type(4))) float f4;

__device__ __constant__ float DT_G[12] = {
    1.0f, 2.154434690031884f, 4.641588833612779f, 10.0f,
    21.54434690031884f, 46.41588833612779f, 100.0f, 215.4434690031884f,
    464.1588833612779f, 1000.0f, 2154.434690031884f, 4641.588833612779f};

__device__ __forceinline__ unsigned short f2bf(float f) {
    __hip_bfloat16 h = __float2bfloat16(f);
    unsigned short u;
    __builtin_memcpy(&u, &h, 2);
    return u;
}

// frag storage index (u16 units) for (row m in tile, k in 0..63)
__device__ __forceinline__ int a_idx(int tile, int m, int k) {
    return tile * 1024 + ((k >> 5) << 9) + (m << 3) + (((k >> 3) & 3) << 7) + (k & 7);
}

// 4x4 transpose of a 16-row tile index (involution). Staging xin rows with this
// permutation makes the Q-MFMA output land in-lane for the attention loop:
// lane(lq,lg) reg j = q[16t + 4j + lg][lq]  ->  qv for m is qacc[m>>2] reg (m&3).
__device__ __forceinline__ int rsw(int r) { return ((r & 3) << 2) | (r >> 2); }

// 16-lane sum via VALU DPP row_ror (no LDS pipe). Order 8,4,2,1 kept bit-exact
// with the verified R5 kernel.
__device__ __forceinline__ float red16(float v) {
    int t;
    t = __builtin_amdgcn_update_dpp(0, __float_as_int(v), 0x128, 0xF, 0xF, true);
    v += __int_as_float(t);
    t = __builtin_amdgcn_update_dpp(0, __float_as_int(v), 0x124, 0xF, 0xF, true);
    v += __int_as_float(t);
    t = __builtin_amdgcn_update_dpp(0, __float_as_int(v), 0x122, 0xF, 0xF, true);
    v += __int_as_float(t);
    t = __builtin_amdgcn_update_dpp(0, __float_as_int(v), 0x121, 0xF, 0xF, true);
    v += __int_as_float(t);
    return v;
}

// ---- prep kernel: build frag-ordered bf16 weights once into workspace ----
// layout: [mat 0..2][h 0..7][ks 0..1][lane 0..63][j 0..7] bf16. qw pre-scaled
// by 0.25 (exact power-of-2, commutes with bf16 rounding + f32 adds).
__global__ void prep_wfrag(const float* __restrict__ qw, const float* __restrict__ kw,
                           const float* __restrict__ vw, unsigned short* __restrict__ wsb) {
    int idx = blockIdx.x * 256 + threadIdx.x;
    if (idx >= 24576) return;
    int j = idx & 7;
    int lane = (idx >> 3) & 63;
    int ks = (idx >> 9) & 1;
    int h = (idx >> 10) & 7;
    int mat = idx >> 13;
    const float* w = (mat == 0) ? qw : (mat == 1) ? kw : vw;
    int k = ks * 32 + ((lane >> 4) << 3) + j;
    int n = (h << 4) + (lane & 15);
    float f = (k < 48) ? w[k * 128 + n] : 0.0f;
    if (mat == 0) f *= 0.25f;
    wsb[idx] = f2bf(f);
}

// ---- merged kernel: conv + staging + MFMA attention, 512 threads ----
struct __align__(16) Smem {
    unsigned short A[10 * 1024]; // [0..1]=xin (32 rows, rsw-permuted), [2..9]=wrp (128 rows)
    float outt[128 * 33];        // out tile [ch][32px], pad 33
    float pbl[192];              // window position bias [v][c]
    float offs[32];              // per-pixel offsets
    float part[8][32];           // conv partial sums (chain q, pixel)
}; // 39296 B -> 4 blocks/CU (needs VGPR <= 64, enforced by launch_bounds)

__global__ __launch_bounds__(512, 8) void fused_kernel(
    const float* __restrict__ y, const float* __restrict__ x,
    const float* __restrict__ cw, const float* __restrict__ cb,
    const float* __restrict__ qb, const float* __restrict__ kb,
    const float* __restrict__ vb, const unsigned short* __restrict__ wsb,
    float* __restrict__ out) {
    __shared__ Smem sm;
    int tid = threadIdx.x;
    int bid = blockIdx.x;
    int b = (bid & 7) * 288 + (bid >> 3); // bijective XCD swizzle (2304 = 8*288)
    int pix0 = b * 32;
    int n = pix0 / HW_;
    int rem0 = pix0 - n * HW_;
    int row0 = rem0 / W_;
    int col0 = rem0 - row0 * W_; // 32 px share one image row (W_%32==0)

    // ---- phase 0: waves 0-3 conv (bit-exact chains); waves 4-7 xin prefetch + pbl ----
    float xv8[8];
    if (tid < 256) {
        int p = tid & 31, q = tid >> 5;
        int col = col0 + p;
        // block-uniform border test; interior path skips mask muls (wp*1.0 == wp)
        bool border = (col0 == 0) || (col0 + 32 == W_) || (row0 == 0) || (row0 == H_ - 1);
        int c_lf = col - (col > 0 ? 1 : 0);
        int c_rt = col + (col < W_ - 1 ? 1 : 0);
        int r_up = row0 - (row0 > 0 ? 1 : 0);
        int r_dn = row0 + (row0 < H_ - 1 ? 1 : 0);
        float k0 = 1.f, k1 = 1.f, k2 = 1.f, k3 = 1.f, k5 = 1.f, k6 = 1.f, k7 = 1.f, k8 = 1.f;
        if (border) {
            float m_lf = (col > 0) ? 1.f : 0.f, m_rt = (col < W_ - 1) ? 1.f : 0.f;
            float m_up = (row0 > 0) ? 1.f : 0.f, m_dn = (row0 < H_ - 1) ? 1.f : 0.f;
            k0 = m_up * m_lf; k1 = m_up; k2 = m_up * m_rt;
            k3 = m_lf; k5 = m_rt;
            k6 = m_dn * m_lf; k7 = m_dn; k8 = m_dn * m_rt;
        }
        int icbase = (q >> 1) * 24 + (q & 1) * 12;
        float acc = 0.f;
#pragma unroll
        for (int g2 = 0; g2 < 4; ++g2) {
            float buf[27];
#pragma unroll
            for (int cc = 0; cc < 3; ++cc) {
                int ic = icbase + g2 * 3 + cc;
                const float* src = (ic < 48) ? y : x;
                int c = (ic < 48) ? ic : ic - 48;
                const float* b0p = src + (size_t)(n * 48 + c) * HW_;
                const float* pu = b0p + (size_t)r_up * W_;
                const float* pm = b0p + (size_t)row0 * W_;
                const float* pd = b0p + (size_t)r_dn * W_;
                buf[cc * 9 + 0] = pu[c_lf];
                buf[cc * 9 + 1] = pu[col];
                buf[cc * 9 + 2] = pu[c_rt];
                buf[cc * 9 + 3] = pm[c_lf];
                buf[cc * 9 + 4] = pm[col];
                buf[cc * 9 + 5] = pm[c_rt];
                buf[cc * 9 + 6] = pd[c_lf];
                buf[cc * 9 + 7] = pd[col];
                buf[cc * 9 + 8] = pd[c_rt];
            }
            if (!border) {
#pragma unroll
                for (int cc = 0; cc < 3; ++cc) {
                    const float* wp = cw + (icbase + g2 * 3 + cc) * 9;
                    acc += buf[cc * 9 + 0] * wp[0];
                    acc += buf[cc * 9 + 1] * wp[1];
                    acc += buf[cc * 9 + 2] * wp[2];
                    acc += buf[cc * 9 + 3] * wp[3];
                    acc += buf[cc * 9 + 4] * wp[4];
                    acc += buf[cc * 9 + 5] * wp[5];
                    acc += buf[cc * 9 + 6] * wp[6];
                    acc += buf[cc * 9 + 7] * wp[7];
                    acc += buf[cc * 9 + 8] * wp[8];
                }
            } else {
#pragma unroll
                for (int cc = 0; cc < 3; ++cc) {
                    const float* wp = cw + (icbase + g2 * 3 + cc) * 9;
                    acc += buf[cc * 9 + 0] * (wp[0] * k0);
                    acc += buf[cc * 9 + 1] * (wp[1] * k1);
                    acc += buf[cc * 9 + 2] * (wp[2] * k2);
                    acc += buf[cc * 9 + 3] * (wp[3] * k3);
                    acc += buf[cc * 9 + 4] * wp[4];
                    acc += buf[cc * 9 + 5] * (wp[5] * k5);
                    acc += buf[cc * 9 + 6] * (wp[6] * k6);
                    acc += buf[cc * 9 + 7] * (wp[7] * k7);
                    acc += buf[cc * 9 + 8] * (wp[8] * k8);
                }
            }
        }
        sm.part[q][p] = acc;
    } else {
        int e = tid - 256, p = e & 31, oct = e >> 5; // oct 0..7
        if (oct < 6) {
            const float* xb = x + (size_t)(n * 48 + oct * 8) * HW_ + rem0 + p;
#pragma unroll
            for (int j = 0; j < 8; ++j) xv8[j] = xb[(size_t)j * HW_];
        }
        if (e < 192) { // window position bias
            int v = e / 48, c = e - (e / 48) * 48;
            int iy = v >> 1, ix = v & 1;
            int cc = (c < 24) ? c : c - 24;
            int sel = (c < 24) ? iy : ix;
            float ee = sel ? (TWO_PI_F / (1.0f + 1e-6f)) : 0.0f;
            float arg = ee / DT_G[cc >> 1];
            sm.pbl[v * 48 + c] = (cc & 1) ? __cosf(arg) : __sinf(arg);
        }
    }
    __syncthreads();
    if (tid < 32) {
        float a = sm.part[0][tid];
#pragma unroll
        for (int s = 1; s < 8; ++s) a += sm.part[s][tid];
        sm.offs[tid] = (a + cb[0]) * (2.0f / (float)W_);
    }
    __syncthreads();

    // ---- phase 2: staging (b128 LDS writes) + early wsb weight-frag loads ----
    int lane = tid & 63, h = tid >> 6;
    int lq = lane & 15, lg = lane >> 4;
    // hoisted global loads: return under the gather/trig below (~L2 latency)
    const int hb = (h << 1) * 64 + lane;
    bfrag qB0 = *(const bfrag*)&wsb[(0 * 1024 + hb) * 8];
    bfrag qB1 = *(const bfrag*)&wsb[(0 * 1024 + hb + 64) * 8];
    bfrag kB0 = *(const bfrag*)&wsb[(1 * 1024 + hb) * 8];
    bfrag kB1 = *(const bfrag*)&wsb[(1 * 1024 + hb + 64) * 8];
    bfrag vB0 = *(const bfrag*)&wsb[(2 * 1024 + hb) * 8];
    bfrag vB1 = *(const bfrag*)&wsb[(2 * 1024 + hb + 64) * 8];

    // wrp gather: tid<384, thread = (row r, oct): octets {oct, oct+3} = 16 ch
    float yv[16];
    int r_w = tid & 127, oct_w = tid >> 7, t_w = 0, m_w = 0, v_w = 0;
    bool do_wrp = tid < 384;
    if (do_wrp) {
        int p = r_w >> 2;
        v_w = r_w & 3;
        float o = sm.offs[p];
        float gx = (float)(col0 + p) + o;
        float fx = floorf(gx);
        int dy = v_w >> 1, dx = v_w & 1;
        int rr = (int)fminf(fmaxf((float)(row0 + dy), 0.0f), 191.0f);
        int ccx = (int)fminf(fmaxf(fx + (float)dx, 0.0f), 191.0f);
        const float* yb = y + (size_t)(n * 48) * HW_ + (size_t)rr * W_ + ccx;
#pragma unroll
        for (int j = 0; j < 8; ++j) yv[j] = yb[(size_t)(oct_w * 8 + j) * HW_];
#pragma unroll
        for (int j = 0; j < 8; ++j) yv[8 + j] = yb[(size_t)((oct_w + 3) * 8 + j) * HW_];
        t_w = 2 + (r_w >> 4);
        m_w = r_w & 15;
    }
    if (tid >= 256) {
        // xin: one b128 per thread; rows rsw-permuted; octets 6,7 = zero pad
        int e = tid - 256, p = e & 31, oct = e >> 5;
        bfrag w0;
        if (oct < 6) {
            float o = sm.offs[p];
            float gx = (float)(col0 + p) + o;
            float fr = gx - floorf(gx);
            float t1 = fr / (2.0f + 1e-6f);
#pragma unroll
            for (int j = 0; j < 8; ++j) {
                float pe;
                if (oct < 3) {
                    pe = (j & 1) ? 1.0f : 0.0f; // frac_y == 0
                } else {
                    int cc = oct * 8 + j - 24;
                    float arg = (t1 * TWO_PI_F) / DT_G[cc >> 1];
                    pe = (cc & 1) ? __cosf(arg) : __sinf(arg);
                }
                w0[j] = (short)f2bf(xv8[j] + pe);
            }
        } else {
#pragma unroll
            for (int j = 0; j < 8; ++j) w0[j] = 0;
        }
        *(bfrag*)&sm.A[a_idx(p >> 4, rsw(p & 15), oct * 8)] = w0;
    } else {
        // zero wrp pad octets 6,7
        int r = tid & 127, o2 = 6 + (tid >> 7);
        bfrag z;
#pragma unroll
        for (int j = 0; j < 8; ++j) z[j] = 0;
        *(bfrag*)&sm.A[a_idx(2 + (r >> 4), r & 15, o2 * 8)] = z;
    }
    if (do_wrp) {
        bfrag w0, w1;
#pragma unroll
        for (int j = 0; j < 8; ++j)
            w0[j] = (short)f2bf(yv[j] + sm.pbl[v_w * 48 + oct_w * 8 + j]);
#pragma unroll
        for (int j = 0; j < 8; ++j)
            w1[j] = (short)f2bf(yv[8 + j] + sm.pbl[v_w * 48 + (oct_w + 3) * 8 + j]);
        *(bfrag*)&sm.A[a_idx(t_w, m_w, oct_w * 8)] = w0;
        *(bfrag*)&sm.A[a_idx(t_w, m_w, (oct_w + 3) * 8)] = w1;
    }
    __syncthreads();

    // ---- phase 3: MFMA projections + register attention, 1 head per wave ----
    float qbv = qb[(h << 4) + lq] * 0.25f; // SCALE folded (exact, with scaled qw)
    float kbv = kb[(h << 4) + lq];
    float vbv = vb[(h << 4) + lq];

    f4 qacc[2];
#pragma unroll
    for (int t = 0; t < 2; ++t) {
        bfrag a0 = *(const bfrag*)&sm.A[t * 1024 + lane * 8];
        bfrag a1 = *(const bfrag*)&sm.A[t * 1024 + 512 + lane * 8];
        f4 a = {qbv, qbv, qbv, qbv};
        a = __builtin_amdgcn_mfma_f32_16x16x32_bf16(a0, qB0, a, 0, 0, 0);
        a = __builtin_amdgcn_mfma_f32_16x16x32_bf16(a1, qB1, a, 0, 0, 0);
        qacc[t] = a;
    }

    // software-pipelined m-loop: prefetch m+1's wrp fragments during compute of m
    bfrag c0 = *(const bfrag*)&sm.A[2 * 1024 + lane * 8];
    bfrag c1 = *(const bfrag*)&sm.A[2 * 1024 + 512 + lane * 8];
#pragma unroll
    for (int m = 0; m < 8; ++m) {
        bfrag n0, n1;
        if (m < 7) {
            n0 = *(const bfrag*)&sm.A[(3 + m) * 1024 + lane * 8];
            n1 = *(const bfrag*)&sm.A[(3 + m) * 1024 + 512 + lane * 8];
        }
        f4 ka = {kbv, kbv, kbv, kbv};
        ka = __builtin_amdgcn_mfma_f32_16x16x32_bf16(c0, kB0, ka, 0, 0, 0);
        ka = __builtin_amdgcn_mfma_f32_16x16x32_bf16(c1, kB1, ka, 0, 0, 0);
        f4 va = {vbv, vbv, vbv, vbv};
        va = __builtin_amdgcn_mfma_f32_16x16x32_bf16(c0, vB0, va, 0, 0, 0);
        va = __builtin_amdgcn_mfma_f32_16x16x32_bf16(c1, vB1, va, 0, 0, 0);

        // q for pixel 4m+lg, dim lq is IN-LANE (rsw staging): qacc[m>>2] reg (m&3)
        f4 qa = qacc[m >> 2];
        float qv = ((m & 3) == 0) ? qa.x : ((m & 3) == 1) ? qa.y
                 : ((m & 3) == 2) ? qa.z : qa.w;
        // SCALE already folded into qW/qb

        float s0 = qv * ka.x, s1 = qv * ka.y, s2 = qv * ka.z, s3 = qv * ka.w;
        s0 = red16(s0);
        s1 = red16(s1);
        s2 = red16(s2);
        s3 = red16(s3);
        float mx = fmaxf(fmaxf(s0, s1), fmaxf(s2, s3));
        float e0 = __expf(s0 - mx), e1 = __expf(s1 - mx);
        float e2 = __expf(s2 - mx), e3 = __expf(s3 - mx);
        float rden = 1.0f / (e0 + e1 + e2 + e3);
        float o = (e0 * va.x + e1 * va.y + e2 * va.z + e3 * va.w) * rden;
        sm.outt[((h << 4) + lq) * 33 + (m << 2) + lg] = o;
        if (m < 7) { c0 = n0; c1 = n1; }
    }
    __syncthreads();

    // ---- phase 4: coalesced flush, all 512 threads ----
    {
        int ch = tid >> 2, q4 = tid & 3;
        const float* sp = &sm.outt[ch * 33 + q4 * 8];
        float4* dst = (float4*)(out + (size_t)(n * 128 + ch) * HW_ + rem0 + q4 * 8);
        dst[0] = make_float4(sp[0], sp[1], sp[2], sp[3]);
        dst[1] = make_float4(sp[4], sp[5], sp[6], sp[7]);
    }
}

extern "C" void kernel_launch(void* const* d_in, const int* in_sizes, int n_in,
                              void* d_out, int out_size, void* d_ws, size_t ws_size,
                              hipStream_t stream) {
    unsigned short* wsb = (unsigned short*)d_ws;
    hipLaunchKernelGGL(prep_wfrag, dim3(96), dim3(256), 0, stream,
                       (const float*)d_in[4], (const float*)d_in[6],
                       (const float*)d_in[8], wsb);
    hipLaunchKernelGGL(fused_kernel, dim3(NPIX_ / 32), dim3(512), 0, stream,
                       (const float*)d_in[0], (const float*)d_in[1],
                       (const float*)d_in[2], (const float*)d_in[3],
                       (const float*)d_in[5], (const float*)d_in[7],
                       (const float*)d_in[9], wsb,
                       (float*)d_out);
}

// Round 9
// 147.206 us; speedup vs baseline: 1.1194x; 1.1194x over previous
//
#include <hip/hip_runtime.h>
#include <hip/hip_bf16.h>

#define HW_ 36864
#define W_ 192
#define H_ 192
#define NPIX_ 73728
#define TWO_PI_F 6.283185307179586f

typedef __attribute__((ext_vector_type(8))) short bfrag;
typedef __attribute__((ext_vector_type(4))) float f4;

__device__ __constant__ float DT_G[12] = {
    1.0f, 2.154434690031884f, 4.641588833612779f, 10.0f,
    21.54434690031884f, 46.41588833612779f, 100.0f, 215.4434690031884f,
    464.1588833612779f, 1000.0f, 2154.434690031884f, 4641.588833612779f};

__device__ __forceinline__ unsigned short f2bf(float f) {
    __hip_bfloat16 h = __float2bfloat16(f);
    unsigned short u;
    __builtin_memcpy(&u, &h, 2);
    return u;
}

// frag storage index (u16 units) for (row m in tile, k in 0..63)
__device__ __forceinline__ int a_idx(int tile, int m, int k) {
    return tile * 1024 + ((k >> 5) << 9) + (m << 3) + (((k >> 3) & 3) << 7) + (k & 7);
}

// 4x4 transpose of a 16-row tile index (involution). Staging xin rows with this
// permutation makes the Q-MFMA output land in-lane for the attention loop:
// lane(lq,lg) reg j = q[16t + 4j + lg][lq]  ->  qv for m is qacc[m>>2] reg (m&3).
__device__ __forceinline__ int rsw(int r) { return ((r & 3) << 2) | (r >> 2); }

// 16-lane sum via VALU DPP row_ror (no LDS pipe). Order 8,4,2,1 kept bit-exact
// with the verified R5 kernel.
__device__ __forceinline__ float red16(float v) {
    int t;
    t = __builtin_amdgcn_update_dpp(0, __float_as_int(v), 0x128, 0xF, 0xF, true);
    v += __int_as_float(t);
    t = __builtin_amdgcn_update_dpp(0, __float_as_int(v), 0x124, 0xF, 0xF, true);
    v += __int_as_float(t);
    t = __builtin_amdgcn_update_dpp(0, __float_as_int(v), 0x122, 0xF, 0xF, true);
    v += __int_as_float(t);
    t = __builtin_amdgcn_update_dpp(0, __float_as_int(v), 0x121, 0xF, 0xF, true);
    v += __int_as_float(t);
    return v;
}

// ---- prep kernel: build frag-ordered bf16 weights once into workspace ----
// layout: [mat 0..2][h 0..7][ks 0..1][lane 0..63][j 0..7] bf16. qw pre-scaled
// by 0.25 (exact power-of-2, commutes with bf16 rounding + f32 adds).
__global__ void prep_wfrag(const float* __restrict__ qw, const float* __restrict__ kw,
                           const float* __restrict__ vw, unsigned short* __restrict__ wsb) {
    int idx = blockIdx.x * 256 + threadIdx.x;
    if (idx >= 24576) return;
    int j = idx & 7;
    int lane = (idx >> 3) & 63;
    int ks = (idx >> 9) & 1;
    int h = (idx >> 10) & 7;
    int mat = idx >> 13;
    const float* w = (mat == 0) ? qw : (mat == 1) ? kw : vw;
    int k = ks * 32 + ((lane >> 4) << 3) + j;
    int n = (h << 4) + (lane & 15);
    float f = (k < 48) ? w[k * 128 + n] : 0.0f;
    if (mat == 0) f *= 0.25f;
    wsb[idx] = f2bf(f);
}

// ---- merged kernel: conv + staging + MFMA attention, 512 threads ----
struct __align__(16) Smem {
    unsigned short A[10 * 1024]; // [0..1]=xin (32 rows, rsw-permuted), [2..9]=wrp (128 rows)
    float outt[128 * 33];        // out tile [ch][32px], pad 33
    float pbl[192];              // window position bias [v][c]
    float offs[32];              // per-pixel offsets
    float part[8][32];           // conv partial sums (chain q, pixel)
}; // 39296 B -> 4 blocks/CU via LDS; (512,4) keeps VGPR cap at 128 (no spill)

__global__ __launch_bounds__(512, 4) void fused_kernel(
    const float* __restrict__ y, const float* __restrict__ x,
    const float* __restrict__ cw, const float* __restrict__ cb,
    const float* __restrict__ qb, const float* __restrict__ kb,
    const float* __restrict__ vb, const unsigned short* __restrict__ wsb,
    float* __restrict__ out) {
    __shared__ Smem sm;
    int tid = threadIdx.x;
    int bid = blockIdx.x;
    int b = (bid & 7) * 288 + (bid >> 3); // bijective XCD swizzle (2304 = 8*288)
    int pix0 = b * 32;
    int n = pix0 / HW_;
    int rem0 = pix0 - n * HW_;
    int row0 = rem0 / W_;
    int col0 = rem0 - row0 * W_; // 32 px share one image row (W_%32==0)

    // ---- phase 0: waves 0-3 conv (bit-exact chains); waves 4-7 xin prefetch + pbl ----
    float xv8[8];
    if (tid < 256) {
        int p = tid & 31, q = tid >> 5;
        int col = col0 + p;
        // block-uniform border test; interior path skips mask muls (wp*1.0 == wp)
        bool border = (col0 == 0) || (col0 + 32 == W_) || (row0 == 0) || (row0 == H_ - 1);
        int c_lf = col - (col > 0 ? 1 : 0);
        int c_rt = col + (col < W_ - 1 ? 1 : 0);
        int r_up = row0 - (row0 > 0 ? 1 : 0);
        int r_dn = row0 + (row0 < H_ - 1 ? 1 : 0);
        float k0 = 1.f, k1 = 1.f, k2 = 1.f, k3 = 1.f, k5 = 1.f, k6 = 1.f, k7 = 1.f, k8 = 1.f;
        if (border) {
            float m_lf = (col > 0) ? 1.f : 0.f, m_rt = (col < W_ - 1) ? 1.f : 0.f;
            float m_up = (row0 > 0) ? 1.f : 0.f, m_dn = (row0 < H_ - 1) ? 1.f : 0.f;
            k0 = m_up * m_lf; k1 = m_up; k2 = m_up * m_rt;
            k3 = m_lf; k5 = m_rt;
            k6 = m_dn * m_lf; k7 = m_dn; k8 = m_dn * m_rt;
        }
        int icbase = (q >> 1) * 24 + (q & 1) * 12;
        float acc = 0.f;
#pragma unroll
        for (int g2 = 0; g2 < 4; ++g2) {
            float buf[27];
#pragma unroll
            for (int cc = 0; cc < 3; ++cc) {
                int ic = icbase + g2 * 3 + cc;
                const float* src = (ic < 48) ? y : x;
                int c = (ic < 48) ? ic : ic - 48;
                const float* b0p = src + (size_t)(n * 48 + c) * HW_;
                const float* pu = b0p + (size_t)r_up * W_;
                const float* pm = b0p + (size_t)row0 * W_;
                const float* pd = b0p + (size_t)r_dn * W_;
                buf[cc * 9 + 0] = pu[c_lf];
                buf[cc * 9 + 1] = pu[col];
                buf[cc * 9 + 2] = pu[c_rt];
                buf[cc * 9 + 3] = pm[c_lf];
                buf[cc * 9 + 4] = pm[col];
                buf[cc * 9 + 5] = pm[c_rt];
                buf[cc * 9 + 6] = pd[c_lf];
                buf[cc * 9 + 7] = pd[col];
                buf[cc * 9 + 8] = pd[c_rt];
            }
            if (!border) {
#pragma unroll
                for (int cc = 0; cc < 3; ++cc) {
                    const float* wp = cw + (icbase + g2 * 3 + cc) * 9;
                    acc += buf[cc * 9 + 0] * wp[0];
                    acc += buf[cc * 9 + 1] * wp[1];
                    acc += buf[cc * 9 + 2] * wp[2];
                    acc += buf[cc * 9 + 3] * wp[3];
                    acc += buf[cc * 9 + 4] * wp[4];
                    acc += buf[cc * 9 + 5] * wp[5];
                    acc += buf[cc * 9 + 6] * wp[6];
                    acc += buf[cc * 9 + 7] * wp[7];
                    acc += buf[cc * 9 + 8] * wp[8];
                }
            } else {
#pragma unroll
                for (int cc = 0; cc < 3; ++cc) {
                    const float* wp = cw + (icbase + g2 * 3 + cc) * 9;
                    acc += buf[cc * 9 + 0] * (wp[0] * k0);
                    acc += buf[cc * 9 + 1] * (wp[1] * k1);
                    acc += buf[cc * 9 + 2] * (wp[2] * k2);
                    acc += buf[cc * 9 + 3] * (wp[3] * k3);
                    acc += buf[cc * 9 + 4] * wp[4];
                    acc += buf[cc * 9 + 5] * (wp[5] * k5);
                    acc += buf[cc * 9 + 6] * (wp[6] * k6);
                    acc += buf[cc * 9 + 7] * (wp[7] * k7);
                    acc += buf[cc * 9 + 8] * (wp[8] * k8);
                }
            }
        }
        sm.part[q][p] = acc;
    } else {
        int e = tid - 256, p = e & 31, oct = e >> 5; // oct 0..7
        if (oct < 6) {
            const float* xb = x + (size_t)(n * 48 + oct * 8) * HW_ + rem0 + p;
#pragma unroll
            for (int j = 0; j < 8; ++j) xv8[j] = xb[(size_t)j * HW_];
        }
        if (e < 192) { // window position bias
            int v = e / 48, c = e - (e / 48) * 48;
            int iy = v >> 1, ix = v & 1;
            int cc = (c < 24) ? c : c - 24;
            int sel = (c < 24) ? iy : ix;
            float ee = sel ? (TWO_PI_F / (1.0f + 1e-6f)) : 0.0f;
            float arg = ee / DT_G[cc >> 1];
            sm.pbl[v * 48 + c] = (cc & 1) ? __cosf(arg) : __sinf(arg);
        }
    }
    __syncthreads();
    if (tid < 32) {
        float a = sm.part[0][tid];
#pragma unroll
        for (int s = 1; s < 8; ++s) a += sm.part[s][tid];
        sm.offs[tid] = (a + cb[0]) * (2.0f / (float)W_);
    }
    __syncthreads();

    // ---- phase 2: staging (b128 LDS writes) + early wsb weight-frag loads ----
    int lane = tid & 63, h = tid >> 6;
    int lq = lane & 15, lg = lane >> 4;
    // hoisted global loads: return under the gather/trig below (~L2 latency)
    const int hb = (h << 1) * 64 + lane;
    bfrag qB0 = *(const bfrag*)&wsb[(0 * 1024 + hb) * 8];
    bfrag qB1 = *(const bfrag*)&wsb[(0 * 1024 + hb + 64) * 8];
    bfrag kB0 = *(const bfrag*)&wsb[(1 * 1024 + hb) * 8];
    bfrag kB1 = *(const bfrag*)&wsb[(1 * 1024 + hb + 64) * 8];
    bfrag vB0 = *(const bfrag*)&wsb[(2 * 1024 + hb) * 8];
    bfrag vB1 = *(const bfrag*)&wsb[(2 * 1024 + hb + 64) * 8];

    // wrp gather: tid<384, thread = (row r, oct): octets {oct, oct+3} = 16 ch
    float yv[16];
    int r_w = tid & 127, oct_w = tid >> 7, t_w = 0, m_w = 0, v_w = 0;
    bool do_wrp = tid < 384;
    if (do_wrp) {
        int p = r_w >> 2;
        v_w = r_w & 3;
        float o = sm.offs[p];
        float gx = (float)(col0 + p) + o;
        float fx = floorf(gx);
        int dy = v_w >> 1, dx = v_w & 1;
        int rr = (int)fminf(fmaxf((float)(row0 + dy), 0.0f), 191.0f);
        int ccx = (int)fminf(fmaxf(fx + (float)dx, 0.0f), 191.0f);
        const float* yb = y + (size_t)(n * 48) * HW_ + (size_t)rr * W_ + ccx;
#pragma unroll
        for (int j = 0; j < 8; ++j) yv[j] = yb[(size_t)(oct_w * 8 + j) * HW_];
#pragma unroll
        for (int j = 0; j < 8; ++j) yv[8 + j] = yb[(size_t)((oct_w + 3) * 8 + j) * HW_];
        t_w = 2 + (r_w >> 4);
        m_w = r_w & 15;
    }
    if (tid >= 256) {
        // xin: one b128 per thread; rows rsw-permuted; octets 6,7 = zero pad
        int e = tid - 256, p = e & 31, oct = e >> 5;
        bfrag w0;
        if (oct < 6) {
            float o = sm.offs[p];
            float gx = (float)(col0 + p) + o;
            float fr = gx - floorf(gx);
            float t1 = fr / (2.0f + 1e-6f);
#pragma unroll
            for (int j = 0; j < 8; ++j) {
                float pe;
                if (oct < 3) {
                    pe = (j & 1) ? 1.0f : 0.0f; // frac_y == 0
                } else {
                    int cc = oct * 8 + j - 24;
                    float arg = (t1 * TWO_PI_F) / DT_G[cc >> 1];
                    pe = (cc & 1) ? __cosf(arg) : __sinf(arg);
                }
                w0[j] = (short)f2bf(xv8[j] + pe);
            }
        } else {
#pragma unroll
            for (int j = 0; j < 8; ++j) w0[j] = 0;
        }
        *(bfrag*)&sm.A[a_idx(p >> 4, rsw(p & 15), oct * 8)] = w0;
    } else {
        // zero wrp pad octets 6,7
        int r = tid & 127, o2 = 6 + (tid >> 7);
        bfrag z;
#pragma unroll
        for (int j = 0; j < 8; ++j) z[j] = 0;
        *(bfrag*)&sm.A[a_idx(2 + (r >> 4), r & 15, o2 * 8)] = z;
    }
    if (do_wrp) {
        bfrag w0, w1;
#pragma unroll
        for (int j = 0; j < 8; ++j)
            w0[j] = (short)f2bf(yv[j] + sm.pbl[v_w * 48 + oct_w * 8 + j]);
#pragma unroll
        for (int j = 0; j < 8; ++j)
            w1[j] = (short)f2bf(yv[8 + j] + sm.pbl[v_w * 48 + (oct_w + 3) * 8 + j]);
        *(bfrag*)&sm.A[a_idx(t_w, m_w, oct_w * 8)] = w0;
        *(bfrag*)&sm.A[a_idx(t_w, m_w, (oct_w + 3) * 8)] = w1;
    }
    __syncthreads();

    // ---- phase 3: MFMA projections + register attention, 1 head per wave ----
    float qbv = qb[(h << 4) + lq] * 0.25f; // SCALE folded (exact, with scaled qw)
    float kbv = kb[(h << 4) + lq];
    float vbv = vb[(h << 4) + lq];

    f4 qacc[2];
#pragma unroll
    for (int t = 0; t < 2; ++t) {
        bfrag a0 = *(const bfrag*)&sm.A[t * 1024 + lane * 8];
        bfrag a1 = *(const bfrag*)&sm.A[t * 1024 + 512 + lane * 8];
        f4 a = {qbv, qbv, qbv, qbv};
        a = __builtin_amdgcn_mfma_f32_16x16x32_bf16(a0, qB0, a, 0, 0, 0);
        a = __builtin_amdgcn_mfma_f32_16x16x32_bf16(a1, qB1, a, 0, 0, 0);
        qacc[t] = a;
    }

    // software-pipelined m-loop: prefetch m+1's wrp fragments during compute of m
    bfrag c0 = *(const bfrag*)&sm.A[2 * 1024 + lane * 8];
    bfrag c1 = *(const bfrag*)&sm.A[2 * 1024 + 512 + lane * 8];
#pragma unroll
    for (int m = 0; m < 8; ++m) {
        bfrag n0, n1;
        if (m < 7) {
            n0 = *(const bfrag*)&sm.A[(3 + m) * 1024 + lane * 8];
            n1 = *(const bfrag*)&sm.A[(3 + m) * 1024 + 512 + lane * 8];
        }
        f4 ka = {kbv, kbv, kbv, kbv};
        ka = __builtin_amdgcn_mfma_f32_16x16x32_bf16(c0, kB0, ka, 0, 0, 0);
        ka = __builtin_amdgcn_mfma_f32_16x16x32_bf16(c1, kB1, ka, 0, 0, 0);
        f4 va = {vbv, vbv, vbv, vbv};
        va = __builtin_amdgcn_mfma_f32_16x16x32_bf16(c0, vB0, va, 0, 0, 0);
        va = __builtin_amdgcn_mfma_f32_16x16x32_bf16(c1, vB1, va, 0, 0, 0);

        // q for pixel 4m+lg, dim lq is IN-LANE (rsw staging): qacc[m>>2] reg (m&3)
        f4 qa = qacc[m >> 2];
        float qv = ((m & 3) == 0) ? qa.x : ((m & 3) == 1) ? qa.y
                 : ((m & 3) == 2) ? qa.z : qa.w;
        // SCALE already folded into qW/qb

        float s0 = qv * ka.x, s1 = qv * ka.y, s2 = qv * ka.z, s3 = qv * ka.w;
        s0 = red16(s0);
        s1 = red16(s1);
        s2 = red16(s2);
        s3 = red16(s3);
        float mx = fmaxf(fmaxf(s0, s1), fmaxf(s2, s3));
        float e0 = __expf(s0 - mx), e1 = __expf(s1 - mx);
        float e2 = __expf(s2 - mx), e3 = __expf(s3 - mx);
        float rden = 1.0f / (e0 + e1 + e2 + e3);
        float o = (e0 * va.x + e1 * va.y + e2 * va.z + e3 * va.w) * rden;
        sm.outt[((h << 4) + lq) * 33 + (m << 2) + lg] = o;
        if (m < 7) { c0 = n0; c1 = n1; }
    }
    __syncthreads();

    // ---- phase 4: coalesced flush, all 512 threads ----
    {
        int ch = tid >> 2, q4 = tid & 3;
        const float* sp = &sm.outt[ch * 33 + q4 * 8];
        float4* dst = (float4*)(out + (size_t)(n * 128 + ch) * HW_ + rem0 + q4 * 8);
        dst[0] = make_float4(sp[0], sp[1], sp[2], sp[3]);
        dst[1] = make_float4(sp[4], sp[5], sp[6], sp[7]);
    }
}

extern "C" void kernel_launch(void* const* d_in, const int* in_sizes, int n_in,
                              void* d_out, int out_size, void* d_ws, size_t ws_size,
                              hipStream_t stream) {
    unsigned short* wsb = (unsigned short*)d_ws;
    hipLaunchKernelGGL(prep_wfrag, dim3(96), dim3(256), 0, stream,
                       (const float*)d_in[4], (const float*)d_in[6],
                       (const float*)d_in[8], wsb);
    hipLaunchKernelGGL(fused_kernel, dim3(NPIX_ / 32), dim3(512), 0, stream,
                       (const float*)d_in[0], (const float*)d_in[1],
                       (const float*)d_in[2], (const float*)d_in[3],
                       (const float*)d_in[5], (const float*)d_in[7],
                       (const float*)d_in[9], wsb,
                       (float*)d_out);
}

// Round 11
// 137.972 us; speedup vs baseline: 1.1943x; 1.0669x over previous
//
#include <hip/hip_runtime.h>
#include <hip/hip_bf16.h>

#define HW_ 36864
#define W_ 192
#define H_ 192
#define NPIX_ 73728
#define TWO_PI_F 6.283185307179586f

typedef __attribute__((ext_vector_type(8))) short bfrag;
typedef __attribute__((ext_vector_type(4))) float f4;

__device__ __constant__ float DT_G[12] = {
    1.0f, 2.154434690031884f, 4.641588833612779f, 10.0f,
    21.54434690031884f, 46.41588833612779f, 100.0f, 215.4434690031884f,
    464.1588833612779f, 1000.0f, 2154.434690031884f, 4641.588833612779f};

__device__ __forceinline__ unsigned short f2bf(float f) {
    __hip_bfloat16 h = __float2bfloat16(f);
    unsigned short u;
    __builtin_memcpy(&u, &h, 2);
    return u;
}

// frag storage index (u16 units) for (row m in tile, k in 0..63)
__device__ __forceinline__ int a_idx(int tile, int m, int k) {
    return tile * 1024 + ((k >> 5) << 9) + (m << 3) + (((k >> 3) & 3) << 7) + (k & 7);
}

// 4x4 transpose of a 16-row tile index (involution). Staging xin rows with this
// permutation makes the Q-MFMA output land in-lane for the attention loop:
// lane(lq,lg) reg j = q[16t + 4j + lg][lq]  ->  qv for m is qacc[m>>2] reg (m&3).
__device__ __forceinline__ int rsw(int r) { return ((r & 3) << 2) | (r >> 2); }

// 16-lane sum via VALU DPP row_ror (no LDS pipe). Order 8,4,2,1 bit-exact with R5.
__device__ __forceinline__ float red16(float v) {
    int t;
    t = __builtin_amdgcn_update_dpp(0, __float_as_int(v), 0x128, 0xF, 0xF, true);
    v += __int_as_float(t);
    t = __builtin_amdgcn_update_dpp(0, __float_as_int(v), 0x124, 0xF, 0xF, true);
    v += __int_as_float(t);
    t = __builtin_amdgcn_update_dpp(0, __float_as_int(v), 0x122, 0xF, 0xF, true);
    v += __int_as_float(t);
    t = __builtin_amdgcn_update_dpp(0, __float_as_int(v), 0x121, 0xF, 0xF, true);
    v += __int_as_float(t);
    return v;
}

// ---- prep kernel: build frag-ordered bf16 weights once into workspace ----
// layout: [mat 0..2][h 0..7][ks 0..1][lane 0..63][j 0..7] bf16. qw pre-scaled
// by 0.25 (exact power-of-2: scales bf16 exponent only, distributes exactly
// over rounded f32 adds -> bit-identical scores; verified absmax R7/R9).
__global__ void prep_wfrag(const float* __restrict__ qw, const float* __restrict__ kw,
                           const float* __restrict__ vw, unsigned short* __restrict__ wsb) {
    int idx = blockIdx.x * 256 + threadIdx.x;
    if (idx >= 24576) return;
    int j = idx & 7;
    int lane = (idx >> 3) & 63;
    int ks = (idx >> 9) & 1;
    int h = (idx >> 10) & 7;
    int mat = idx >> 13;
    const float* w = (mat == 0) ? qw : (mat == 1) ? kw : vw;
    int k = ks * 32 + ((lane >> 4) << 3) + j;
    int n = (h << 4) + (lane & 15);
    float f = (k < 48) ? w[k * 128 + n] : 0.0f;
    if (mat == 0) f *= 0.25f;
    wsb[idx] = f2bf(f);
}

// ---- merged kernel: conv + staging + MFMA attention, 512 threads ----
struct __align__(16) Smem {
    unsigned short A[10 * 1024]; // [0..1]=xin (32 rows, rsw-permuted), [2..9]=wrp (128 rows)
    float outt[128 * 33];        // out tile [ch][32px], pad 33
    float pbl[192];              // window position bias [v][c]
    float offs[32];              // per-pixel offsets
    float part[8][32];           // conv partial sums (chain q, pixel)
}; // 39296 B -> 4 blocks/CU; R5 codegen fits 36 VGPR at (512,8) with no spill

__global__ __launch_bounds__(512, 8) void fused_kernel(
    const float* __restrict__ y, const float* __restrict__ x,
    const float* __restrict__ cw, const float* __restrict__ cb,
    const float* __restrict__ qb, const float* __restrict__ kb,
    const float* __restrict__ vb, const unsigned short* __restrict__ wsb,
    float* __restrict__ out) {
    __shared__ Smem sm;
    int tid = threadIdx.x;
    int bid = blockIdx.x;
    int b = (bid & 7) * 288 + (bid >> 3); // bijective XCD swizzle (2304 = 8*288)
    int pix0 = b * 32;
    int n = pix0 / HW_;
    int rem0 = pix0 - n * HW_;
    int row0 = rem0 / W_;
    int col0 = rem0 - row0 * W_; // 32 px share one image row (W_%32==0)

    // ---- phase 0: waves 0-3 conv (bit-exact chains); waves 4-7 xin prefetch + pbl ----
    float xv8[8];
    if (tid < 256) {
        int p = tid & 31, q = tid >> 5;
        int col = col0 + p;
        // block-uniform border test; interior blocks skip the mask multiplies
        // (wp[t]*1.0f == wp[t] bitwise -> identical results). Masks are
        // block/lane-uniform scalars -> no VGPR pressure.
        bool border = (col0 == 0) || (col0 + 32 == W_) || (row0 == 0) || (row0 == H_ - 1);
        int c_lf = col - (col > 0 ? 1 : 0);
        int c_rt = col + (col < W_ - 1 ? 1 : 0);
        int r_up = row0 - (row0 > 0 ? 1 : 0);
        int r_dn = row0 + (row0 < H_ - 1 ? 1 : 0);
        int icbase = (q >> 1) * 24 + (q & 1) * 12;
        float acc = 0.f;
        if (!border) {
#pragma unroll
            for (int g2 = 0; g2 < 4; ++g2) {
                float buf[27];
#pragma unroll
                for (int cc = 0; cc < 3; ++cc) {
                    int ic = icbase + g2 * 3 + cc;
                    const float* src = (ic < 48) ? y : x;
                    int c = (ic < 48) ? ic : ic - 48;
                    const float* b0p = src + (size_t)(n * 48 + c) * HW_;
                    const float* pu = b0p + (size_t)r_up * W_;
                    const float* pm = b0p + (size_t)row0 * W_;
                    const float* pd = b0p + (size_t)r_dn * W_;
                    buf[cc * 9 + 0] = pu[c_lf];
                    buf[cc * 9 + 1] = pu[col];
                    buf[cc * 9 + 2] = pu[c_rt];
                    buf[cc * 9 + 3] = pm[c_lf];
                    buf[cc * 9 + 4] = pm[col];
                    buf[cc * 9 + 5] = pm[c_rt];
                    buf[cc * 9 + 6] = pd[c_lf];
                    buf[cc * 9 + 7] = pd[col];
                    buf[cc * 9 + 8] = pd[c_rt];
                }
#pragma unroll
                for (int cc = 0; cc < 3; ++cc) {
                    const float* wp = cw + (icbase + g2 * 3 + cc) * 9;
                    acc += buf[cc * 9 + 0] * wp[0];
                    acc += buf[cc * 9 + 1] * wp[1];
                    acc += buf[cc * 9 + 2] * wp[2];
                    acc += buf[cc * 9 + 3] * wp[3];
                    acc += buf[cc * 9 + 4] * wp[4];
                    acc += buf[cc * 9 + 5] * wp[5];
                    acc += buf[cc * 9 + 6] * wp[6];
                    acc += buf[cc * 9 + 7] * wp[7];
                    acc += buf[cc * 9 + 8] * wp[8];
                }
            }
        } else {
            float m_lf = (col > 0) ? 1.f : 0.f, m_rt = (col < W_ - 1) ? 1.f : 0.f;
            float m_up = (row0 > 0) ? 1.f : 0.f, m_dn = (row0 < H_ - 1) ? 1.f : 0.f;
            float k0 = m_up * m_lf, k1 = m_up, k2 = m_up * m_rt;
            float k3 = m_lf, k5 = m_rt;
            float k6 = m_dn * m_lf, k7 = m_dn, k8 = m_dn * m_rt;
#pragma unroll
            for (int g2 = 0; g2 < 4; ++g2) {
                float buf[27];
#pragma unroll
                for (int cc = 0; cc < 3; ++cc) {
                    int ic = icbase + g2 * 3 + cc;
                    const float* src = (ic < 48) ? y : x;
                    int c = (ic < 48) ? ic : ic - 48;
                    const float* b0p = src + (size_t)(n * 48 + c) * HW_;
                    const float* pu = b0p + (size_t)r_up * W_;
                    const float* pm = b0p + (size_t)row0 * W_;
                    const float* pd = b0p + (size_t)r_dn * W_;
                    buf[cc * 9 + 0] = pu[c_lf];
                    buf[cc * 9 + 1] = pu[col];
                    buf[cc * 9 + 2] = pu[c_rt];
                    buf[cc * 9 + 3] = pm[c_lf];
                    buf[cc * 9 + 4] = pm[col];
                    buf[cc * 9 + 5] = pm[c_rt];
                    buf[cc * 9 + 6] = pd[c_lf];
                    buf[cc * 9 + 7] = pd[col];
                    buf[cc * 9 + 8] = pd[c_rt];
                }
#pragma unroll
                for (int cc = 0; cc < 3; ++cc) {
                    const float* wp = cw + (icbase + g2 * 3 + cc) * 9;
                    acc += buf[cc * 9 + 0] * (wp[0] * k0);
                    acc += buf[cc * 9 + 1] * (wp[1] * k1);
                    acc += buf[cc * 9 + 2] * (wp[2] * k2);
                    acc += buf[cc * 9 + 3] * (wp[3] * k3);
                    acc += buf[cc * 9 + 4] * wp[4];
                    acc += buf[cc * 9 + 5] * (wp[5] * k5);
                    acc += buf[cc * 9 + 6] * (wp[6] * k6);
                    acc += buf[cc * 9 + 7] * (wp[7] * k7);
                    acc += buf[cc * 9 + 8] * (wp[8] * k8);
                }
            }
        }
        sm.part[q][p] = acc;
    } else {
        int e = tid - 256, p = e & 31, oct = e >> 5; // oct 0..7
        if (oct < 6) {
            const float* xb = x + (size_t)(n * 48 + oct * 8) * HW_ + rem0 + p;
#pragma unroll
            for (int j = 0; j < 8; ++j) xv8[j] = xb[(size_t)j * HW_];
        }
        if (e < 192) { // window position bias
            int v = e / 48, c = e - (e / 48) * 48;
            int iy = v >> 1, ix = v & 1;
            int cc = (c < 24) ? c : c - 24;
            int sel = (c < 24) ? iy : ix;
            float ee = sel ? (TWO_PI_F / (1.0f + 1e-6f)) : 0.0f;
            float arg = ee / DT_G[cc >> 1];
            sm.pbl[v * 48 + c] = (cc & 1) ? __cosf(arg) : __sinf(arg);
        }
    }
    __syncthreads();
    if (tid < 32) {
        float a = sm.part[0][tid];
#pragma unroll
        for (int s = 1; s < 8; ++s) a += sm.part[s][tid];
        sm.offs[tid] = (a + cb[0]) * (2.0f / (float)W_);
    }
    __syncthreads();

    // ---- phase 2: staging (b128 LDS writes) ----
    // wrp gather: tid<384, thread = (row r, oct): octets {oct, oct+3} = 16 ch
    float yv[16];
    int r_w = tid & 127, oct_w = tid >> 7, t_w = 0, m_w = 0, v_w = 0;
    bool do_wrp = tid < 384;
    if (do_wrp) {
        int p = r_w >> 2;
        v_w = r_w & 3;
        float o = sm.offs[p];
        float gx = (float)(col0 + p) + o;
        float fx = floorf(gx);
        int dy = v_w >> 1, dx = v_w & 1;
        int rr = (int)fminf(fmaxf((float)(row0 + dy), 0.0f), 191.0f);
        int ccx = (int)fminf(fmaxf(fx + (float)dx, 0.0f), 191.0f);
        const float* yb = y + (size_t)(n * 48) * HW_ + (size_t)rr * W_ + ccx;
#pragma unroll
        for (int j = 0; j < 8; ++j) yv[j] = yb[(size_t)(oct_w * 8 + j) * HW_];
#pragma unroll
        for (int j = 0; j < 8; ++j) yv[8 + j] = yb[(size_t)((oct_w + 3) * 8 + j) * HW_];
        t_w = 2 + (r_w >> 4);
        m_w = r_w & 15;
    }
    if (tid >= 256) {
        // xin: one b128 per thread; rows rsw-permuted; octets 6,7 = zero pad
        int e = tid - 256, p = e & 31, oct = e >> 5;
        bfrag w0;
        if (oct < 6) {
            float o = sm.offs[p];
            float gx = (float)(col0 + p) + o;
            float fr = gx - floorf(gx);
            float t1 = fr / (2.0f + 1e-6f);
#pragma unroll
            for (int j = 0; j < 8; ++j) {
                float pe;
                if (oct < 3) {
                    pe = (j & 1) ? 1.0f : 0.0f; // frac_y == 0
                } else {
                    int cc = oct * 8 + j - 24;
                    float arg = (t1 * TWO_PI_F) / DT_G[cc >> 1];
                    pe = (cc & 1) ? __cosf(arg) : __sinf(arg);
                }
                w0[j] = (short)f2bf(xv8[j] + pe);
            }
        } else {
#pragma unroll
            for (int j = 0; j < 8; ++j) w0[j] = 0;
        }
        *(bfrag*)&sm.A[a_idx(p >> 4, rsw(p & 15), oct * 8)] = w0;
    } else {
        // zero wrp pad octets 6,7
        int r = tid & 127, o2 = 6 + (tid >> 7);
        bfrag z;
#pragma unroll
        for (int j = 0; j < 8; ++j) z[j] = 0;
        *(bfrag*)&sm.A[a_idx(2 + (r >> 4), r & 15, o2 * 8)] = z;
    }
    if (do_wrp) {
        bfrag w0, w1;
#pragma unroll
        for (int j = 0; j < 8; ++j)
            w0[j] = (short)f2bf(yv[j] + sm.pbl[v_w * 48 + oct_w * 8 + j]);
#pragma unroll
        for (int j = 0; j < 8; ++j)
            w1[j] = (short)f2bf(yv[8 + j] + sm.pbl[v_w * 48 + (oct_w + 3) * 8 + j]);
        *(bfrag*)&sm.A[a_idx(t_w, m_w, oct_w * 8)] = w0;
        *(bfrag*)&sm.A[a_idx(t_w, m_w, (oct_w + 3) * 8)] = w1;
    }
    __syncthreads();

    // ---- phase 3: MFMA projections + register attention, 1 head per wave ----
    // (weight loads at phase-3 top, straight-line m-loop: the R5 form the
    //  compiler schedules best — R8/R9 manual pipelining regressed)
    int lane = tid & 63, h = tid >> 6;
    int lq = lane & 15, lg = lane >> 4;
    float qbv = qb[(h << 4) + lq] * 0.25f; // SCALE folded (exact, with scaled qw)
    float kbv = kb[(h << 4) + lq];
    float vbv = vb[(h << 4) + lq];

    const int hb = (h << 1) * 64 + lane;
    bfrag qB0 = *(const bfrag*)&wsb[(0 * 1024 + hb) * 8];
    bfrag qB1 = *(const bfrag*)&wsb[(0 * 1024 + hb + 64) * 8];
    bfrag kB0 = *(const bfrag*)&wsb[(1 * 1024 + hb) * 8];
    bfrag kB1 = *(const bfrag*)&wsb[(1 * 1024 + hb + 64) * 8];
    bfrag vB0 = *(const bfrag*)&wsb[(2 * 1024 + hb) * 8];
    bfrag vB1 = *(const bfrag*)&wsb[(2 * 1024 + hb + 64) * 8];

    f4 qacc[2];
#pragma unroll
    for (int t = 0; t < 2; ++t) {
        bfrag a0 = *(const bfrag*)&sm.A[t * 1024 + lane * 8];
        bfrag a1 = *(const bfrag*)&sm.A[t * 1024 + 512 + lane * 8];
        f4 a = {qbv, qbv, qbv, qbv};
        a = __builtin_amdgcn_mfma_f32_16x16x32_bf16(a0, qB0, a, 0, 0, 0);
        a = __builtin_amdgcn_mfma_f32_16x16x32_bf16(a1, qB1, a, 0, 0, 0);
        qacc[t] = a;
    }

#pragma unroll
    for (int m = 0; m < 8; ++m) {
        bfrag a0 = *(const bfrag*)&sm.A[(2 + m) * 1024 + lane * 8];
        bfrag a1 = *(const bfrag*)&sm.A[(2 + m) * 1024 + 512 + lane * 8];
        f4 ka = {kbv, kbv, kbv, kbv};
        ka = __builtin_amdgcn_mfma_f32_16x16x32_bf16(a0, kB0, ka, 0, 0, 0);
        ka = __builtin_amdgcn_mfma_f32_16x16x32_bf16(a1, kB1, ka, 0, 0, 0);
        f4 va = {vbv, vbv, vbv, vbv};
        va = __builtin_amdgcn_mfma_f32_16x16x32_bf16(a0, vB0, va, 0, 0, 0);
        va = __builtin_amdgcn_mfma_f32_16x16x32_bf16(a1, vB1, va, 0, 0, 0);

        // q for pixel 4m+lg, dim lq is IN-LANE (rsw staging): qacc[m>>2] reg (m&3)
        f4 qa = qacc[m >> 2];
        float qv = ((m & 3) == 0) ? qa.x : ((m & 3) == 1) ? qa.y
                 : ((m & 3) == 2) ? qa.z : qa.w;
        // SCALE already folded into qW/qb

        float s0 = qv * ka.x, s1 = qv * ka.y, s2 = qv * ka.z, s3 = qv * ka.w;
        s0 = red16(s0);
        s1 = red16(s1);
        s2 = red16(s2);
        s3 = red16(s3);
        float mx = fmaxf(fmaxf(s0, s1), fmaxf(s2, s3));
        float e0 = __expf(s0 - mx), e1 = __expf(s1 - mx);
        float e2 = __expf(s2 - mx), e3 = __expf(s3 - mx);
        float rden = 1.0f / (e0 + e1 + e2 + e3);
        float o = (e0 * va.x + e1 * va.y + e2 * va.z + e3 * va.w) * rden;
        sm.outt[((h << 4) + lq) * 33 + (m << 2) + lg] = o;
    }
    __syncthreads();

    // ---- phase 4: coalesced flush, all 512 threads ----
    {
        int ch = tid >> 2, q4 = tid & 3;
        const float* sp = &sm.outt[ch * 33 + q4 * 8];
        float4* dst = (float4*)(out + (size_t)(n * 128 + ch) * HW_ + rem0 + q4 * 8);
        dst[0] = make_float4(sp[0], sp[1], sp[2], sp[3]);
        dst[1] = make_float4(sp[4], sp[5], sp[6], sp[7]);
    }
}

extern "C" void kernel_launch(void* const* d_in, const int* in_sizes, int n_in,
                              void* d_out, int out_size, void* d_ws, size_t ws_size,
                              hipStream_t stream) {
    unsigned short* wsb = (unsigned short*)d_ws;
    hipLaunchKernelGGL(prep_wfrag, dim3(96), dim3(256), 0, stream,
                       (const float*)d_in[4], (const float*)d_in[6],
                       (const float*)d_in[8], wsb);
    hipLaunchKernelGGL(fused_kernel, dim3(NPIX_ / 32), dim3(512), 0, stream,
                       (const float*)d_in[0], (const float*)d_in[1],
                       (const float*)d_in[2], (const float*)d_in[3],
                       (const float*)d_in[5], (const float*)d_in[7],
                       (const float*)d_in[9], wsb,
                       (float*)d_out);
}